// Round 16
// baseline (119.001 us; speedup 1.0000x reference)
//
#include <hip/hip_runtime.h>
#include <cstdint>
#include <cstddef>

using u16 = unsigned short;
using u8  = unsigned char;
typedef short short8 __attribute__((ext_vector_type(8)));
typedef __bf16 bf16x8 __attribute__((ext_vector_type(8)));
typedef float f32x4 __attribute__((ext_vector_type(4)));
typedef u16 u16x4 __attribute__((ext_vector_type(4)));
typedef int i32x4 __attribute__((ext_vector_type(4)));
typedef int i32x8 __attribute__((ext_vector_type(8)));

__device__ __forceinline__ u8 f2fp8(float f) {
  return (u8)(__builtin_amdgcn_cvt_pk_fp8_f32(f, f, 0, 0) & 0xFF);
}

__device__ __forceinline__ void gload16(const void* g, void* l) {
  __builtin_amdgcn_global_load_lds(
      (const __attribute__((address_space(1))) void*)g,
      (__attribute__((address_space(3))) void*)l, 16, 0, 0);
}

// =====================================================================
// MX-fp8 GEMM skeleton (R9/R13, proven ~22us chain; SIMPLE epilogues
// only — complex epilogues on the 128-AGPR accumulator spill, R13).
// =====================================================================
#define MFMAQ8(M0, N0, AF, BF)                                             \
  {                                                                        \
    _Pragma("unroll") for (int m_ = 0; m_ < 4; ++m_) {                     \
      _Pragma("unroll") for (int n_ = 0; n_ < 2; ++n_) {                   \
        acc[(M0) + m_][(N0) + n_] =                                        \
            __builtin_amdgcn_mfma_scale_f32_16x16x128_f8f6f4(              \
                AF[m_], BF[n_], acc[(M0) + m_][(N0) + n_],                 \
                0, 0, 0, 127, 0, 127);                                     \
      }                                                                    \
    }                                                                      \
  }

__device__ __forceinline__ void fp8_core(
    const u8* __restrict__ A, const u8* __restrict__ Bt,
    int arow0, int brow0, u8* lds, f32x4 (&acc)[8][4],
    int lane, int wid, int wr, int wc, int li)
{
  constexpr int Kb = 1024, NT = 8;
  const int Rl = lane >> 3;
  const int sc16 = ((lane & 7) ^ Rl) << 4;
  const int wid2 = wid * 2;
  const int hk = lane >> 4;
  const int c0b = (((hk << 1) + 0) ^ (li & 7)) << 4;
  const int c1b = (((hk << 1) + 1) ^ (li & 7)) << 4;

  auto STAGE = [&](const u8* G, int growbase, int tau, int ldsoff) {
#pragma unroll
    for (int l = 0; l < 2; ++l) {
      const u8* g = G + (size_t)(growbase + (wid2 + l) * 8 + Rl) * Kb +
                    tau * 128 + sc16;
      gload16(g, lds + ldsoff + (wid2 + l) * 1024);
    }
  };
  auto RD = [&](const u8* base, int row) -> i32x8 {
    const u8* p = base + row * 128;
    i32x4 lo = *reinterpret_cast<const i32x4*>(p + c0b);
    i32x4 hi = *reinterpret_cast<const i32x4*>(p + c1b);
    i32x8 r;
    r[0] = lo[0]; r[1] = lo[1]; r[2] = lo[2]; r[3] = lo[3];
    r[4] = hi[0]; r[5] = hi[1]; r[6] = hi[2]; r[7] = hi[3];
    return r;
  };

  i32x8 aa[4], bb01[2], bb23[2];

  STAGE(Bt, brow0 + 0,   0, 65536 + 0);
  STAGE(Bt, brow0 + 128, 0, 65536 + 16384);
  STAGE(A,  arow0 + 0,   0, 0);
  STAGE(A,  arow0 + 128, 0, 16384);
  STAGE(Bt, brow0 + 0,   1, 65536 + 32768);
  STAGE(Bt, brow0 + 128, 1, 65536 + 32768 + 16384);
  STAGE(A,  arow0 + 0,   1, 32768);
  STAGE(A,  arow0 + 128, 1, 32768 + 16384);
  asm volatile("s_waitcnt vmcnt(8)" ::: "memory");
  __builtin_amdgcn_s_barrier();

  {
    const u8* Ab0 = lds + wr * 16384;
    const u8* Bb0 = lds + 65536 + wc * 8192;
#pragma unroll
    for (int m = 0; m < 4; ++m) aa[m] = RD(Ab0, m * 16 + li);
#pragma unroll
    for (int n = 0; n < 2; ++n) bb01[n] = RD(Bb0, n * 16 + li);
  }

  for (int tau = 0; tau < NT; ++tau) {
    const int cur = tau & 1, nxt = cur ^ 1;
    const u8* Ab  = lds + cur * 32768 + wr * 16384;
    const u8* Bb  = lds + 65536 + cur * 32768 + wc * 8192;
    const u8* Abn = lds + nxt * 32768 + wr * 16384;
    const u8* Bbn = lds + 65536 + nxt * 32768 + wc * 8192;

#pragma unroll
    for (int n = 0; n < 2; ++n) bb23[n] = RD(Bb, 32 + n * 16 + li);
    asm volatile("s_waitcnt lgkmcnt(4)" ::: "memory");
    __builtin_amdgcn_sched_barrier(0);
    __builtin_amdgcn_s_setprio(1);
    MFMAQ8(0, 0, aa, bb01);
    __builtin_amdgcn_s_setprio(0);

    asm volatile("s_waitcnt lgkmcnt(0)" ::: "memory");
    __builtin_amdgcn_sched_barrier(0);
    __builtin_amdgcn_s_setprio(1);
    MFMAQ8(0, 2, aa, bb23);
    __builtin_amdgcn_s_setprio(0);
    __builtin_amdgcn_sched_barrier(0);
#pragma unroll
    for (int m = 0; m < 4; ++m) aa[m] = RD(Ab, (m + 4) * 16 + li);
    __builtin_amdgcn_s_barrier();

    if (tau + 2 < NT) {
      STAGE(Bt, brow0 + 0,   tau + 2, 65536 + cur * 32768);
      STAGE(Bt, brow0 + 128, tau + 2, 65536 + cur * 32768 + 16384);
    }
    asm volatile("s_waitcnt lgkmcnt(0)" ::: "memory");
    __builtin_amdgcn_sched_barrier(0);
    __builtin_amdgcn_s_setprio(1);
    MFMAQ8(4, 2, aa, bb23);
    __builtin_amdgcn_s_setprio(0);
    __builtin_amdgcn_s_barrier();

    if (tau + 2 < NT) {
      STAGE(A, arow0 + 0,   tau + 2, cur * 32768);
      STAGE(A, arow0 + 128, tau + 2, cur * 32768 + 16384);
      asm volatile("s_waitcnt vmcnt(8)" ::: "memory");
    } else if (tau + 1 < NT) {
      asm volatile("s_waitcnt vmcnt(0)" ::: "memory");
    }
    __builtin_amdgcn_s_barrier();
    __builtin_amdgcn_s_setprio(1);
    MFMAQ8(4, 0, aa, bb01);
    __builtin_amdgcn_s_setprio(0);
    __builtin_amdgcn_sched_barrier(0);
    if (tau + 1 < NT) {
#pragma unroll
      for (int m = 0; m < 4; ++m) aa[m] = RD(Abn, m * 16 + li);
#pragma unroll
      for (int n = 0; n < 2; ++n) bb01[n] = RD(Bbn, n * 16 + li);
    }
  }
}

// ---------------- MLP GEMM (fp8): relu(acc/512 + b) ----------------
template <int EPI>
__global__ __launch_bounds__(512, 2) void gemm_fp8(
    const u8* __restrict__ A, const u8* __restrict__ Bt,
    const float* __restrict__ bias,
    u8* __restrict__ C8, float* __restrict__ Cf)
{
  constexpr int N = 1024;
  __shared__ alignas(16) u8 lds[131072];
  const int t = (int)threadIdx.x;
  const int lane = t & 63, wid = t >> 6;
  const int wr = wid >> 2, wc = wid & 3;
  const int li = lane & 15, hk = lane >> 4;

  const int orig = (int)blockIdx.x;
  const int cpx = (int)gridDim.x >> 3;
  const int swz = (orig & 7) * cpx + (orig >> 3);
  const int bm = swz >> 2, bn = swz & 3;
  const int arow0 = bm * 256, brow0 = bn * 256;

  f32x4 acc[8][4];
#pragma unroll
  for (int m = 0; m < 8; ++m)
#pragma unroll
    for (int n = 0; n < 4; ++n)
#pragma unroll
      for (int j = 0; j < 4; ++j) acc[m][n][j] = 0.0f;

  fp8_core(A, Bt, arow0, brow0, lds, acc, lane, wid, wr, wc, li);

#pragma unroll
  for (int m = 0; m < 8; ++m) {
#pragma unroll
    for (int n = 0; n < 4; ++n) {
      const int gcol = brow0 + wc * 64 + n * 16 + li;
      const float bv = bias[gcol];
#pragma unroll
      for (int j = 0; j < 4; ++j) {
        const int grow = arow0 + wr * 128 + m * 16 + hk * 4 + j;
        float v = fmaxf(acc[m][n][j] * 0.001953125f + bv, 0.0f);
        if (EPI == 0) {
          C8[(size_t)grow * N + gcol] = f2fp8(v * 8.0f);
        } else {
          int tensor = grow >> 13, rr = grow & 8191;
          int tt = rr >> 3, b_ = rr & 7;
          Cf[(size_t)tensor * 8388608 + (size_t)b_ * 1048576 +
             (size_t)tt * 1024 + gcol] = v;
        }
      }
    }
  }
}

// ---------------- Gram GEMM (fp8): G = Z Z^T / 256, plain f32 store ----
// 64 blocks (8x8 of 256^2). Epilogue is the proven no-spill simple-store
// shape (R13's spill came from fusing exp/atomics onto acc[8][4]).
__global__ __launch_bounds__(512, 2) void gram_fp8(
    const u8* __restrict__ Z8, float* __restrict__ G)
{
  __shared__ alignas(16) u8 lds[131072];
  const int t = (int)threadIdx.x;
  const int lane = t & 63, wid = t >> 6;
  const int wr = wid >> 2, wc = wid & 3;
  const int li = lane & 15, hk = lane >> 4;

  const int orig = (int)blockIdx.x;           // 64 blocks
  const int swz = (orig & 7) * 8 + (orig >> 3);
  const int bm = swz >> 3, bn = swz & 7;
  const int arow0 = bm * 256, brow0 = bn * 256;

  f32x4 acc[8][4];
#pragma unroll
  for (int m = 0; m < 8; ++m)
#pragma unroll
    for (int n = 0; n < 4; ++n)
#pragma unroll
      for (int j = 0; j < 4; ++j) acc[m][n][j] = 0.0f;

  fp8_core(Z8, Z8, arow0, brow0, lds, acc, lane, wid, wr, wc, li);

#pragma unroll
  for (int m = 0; m < 8; ++m) {
#pragma unroll
    for (int n = 0; n < 4; ++n) {
      const int gcol = brow0 + wc * 64 + n * 16 + li;
#pragma unroll
      for (int j = 0; j < 4; ++j) {
        const int grow = arow0 + wr * 128 + m * 16 + hk * 4 + j;
        G[(size_t)grow * 2048 + gcol] = acc[m][n][j] * 0.00390625f;
      }
    }
  }
}

// ---------------- sim_reduce: S[row] = sum_col w*exp(10*G'); dots fold ----
// G' = G with exact-1.0 diagonal. Memory-bound: 16.8MB read.
__global__ __launch_bounds__(256) void sim_reduce(
    const float* __restrict__ G, float* __restrict__ S,
    float* __restrict__ dots)
{
  const int row = (int)blockIdx.x;
  const int t = (int)threadIdx.x;
  const float* gp = G + (size_t)row * 2048 + t * 8;
  float4 v0 = *reinterpret_cast<const float4*>(gp);
  float4 v1 = *reinterpret_cast<const float4*>(gp + 4);
  float vals[8] = {v0.x, v0.y, v0.z, v0.w, v1.x, v1.y, v1.z, v1.w};
  float s = 0.0f, d = 0.0f;
#pragma unroll
  for (int e = 0; e < 8; ++e) {
    int col = t * 8 + e;
    float g = vals[e];
    float logit = (col == row) ? 10.0f : g * 10.0f;
    float w = (col == 0 || col == 1023 || col == 1024 || col == 2047)
                  ? 1.0f : 2.0f;
    s += w * expf(logit);
    if (col == row + 1 && (row & 1023) != 1023) d += g;
  }
#pragma unroll
  for (int o = 1; o < 64; o <<= 1) {
    s += __shfl_xor(s, o);
    d += __shfl_xor(d, o);
  }
  __shared__ float rs[4], rd[4];
  if ((t & 63) == 0) { rs[t >> 6] = s; rd[t >> 6] = d; }
  __syncthreads();
  if (t == 0) {
    S[row] = rs[0] + rs[1] + rs[2] + rs[3];
    float dd = rd[0] + rd[1] + rd[2] + rd[3];
    atomicAdd(dots, dd);
  }
}

// ---------------- fused prep: convert_x(fp8,x8) + transpose W(fp8,x64) + zero dots
__global__ void prep_kernel(const float* __restrict__ h1,
                            const float* __restrict__ h2,
                            const float* __restrict__ W1,
                            const float* __restrict__ W2,
                            u8* __restrict__ X8,
                            u8* __restrict__ W1t,
                            u8* __restrict__ W2t,
                            float* __restrict__ S)
{
  __shared__ float tile[32][33];
  int bid = (int)blockIdx.x;
  if (bid < 16384) {
    size_t i4 = ((size_t)bid * 256 + threadIdx.x) * 4;
    const float* src = (i4 < 8388608) ? (h1 + i4) : (h2 + (i4 - 8388608));
    float4 v = *reinterpret_cast<const float4*>(src);
    int lo = __builtin_amdgcn_cvt_pk_fp8_f32(v.x * 8.0f, v.y * 8.0f, 0, 0);
    int all4 = __builtin_amdgcn_cvt_pk_fp8_f32(v.z * 8.0f, v.w * 8.0f, lo, 1);
    *reinterpret_cast<uint32_t*>(X8 + i4) = (uint32_t)all4;
    return;
  }
  bid -= 16384;
  const float* W;
  u8* Wt;
  if (bid < 1024) {
    W = W1; Wt = W1t;
  } else if (bid < 2048) {
    W = W2; Wt = W2t; bid -= 1024;
  } else {
    for (int i = (int)threadIdx.x; i < 2064; i += 256) S[i] = 0.0f;
    return;
  }
  const int bx = bid & 31, by = bid >> 5;
  const int tx = (int)threadIdx.x & 31, ty = (int)threadIdx.x >> 5;
#pragma unroll
  for (int i = 0; i < 4; ++i)
    tile[ty + i * 8][tx] = W[(size_t)(by * 32 + ty + i * 8) * 1024 + bx * 32 + tx];
  __syncthreads();
#pragma unroll
  for (int i = 0; i < 4; ++i)
    Wt[(size_t)(bx * 32 + ty + i * 8) * 1024 + by * 32 + tx] =
        f2fp8(tile[tx][ty + i * 8] * 64.0f);
}

// ---------------- row_normalize: out rows -> fp8 z*16 (R13-proven) ----------------
__global__ void row_normalize(const float* __restrict__ out, u8* __restrict__ Z8)
{
  const int row = (int)blockIdx.x;   // 0..2047
  const int t = (int)threadIdx.x;    // 256
  const float* src = out + ((row < 1024)
      ? ((size_t)7 * 1048576 + (size_t)row * 1024)
      : ((size_t)8388608 + (size_t)7 * 1048576 + (size_t)(row - 1024) * 1024));
  float4 v = reinterpret_cast<const float4*>(src)[t];
  float ss = v.x * v.x + v.y * v.y + v.z * v.z + v.w * v.w;
#pragma unroll
  for (int d = 1; d < 64; d <<= 1) ss += __shfl_xor(ss, d);
  __shared__ float red[4];
  if ((t & 63) == 0) red[t >> 6] = ss;
  __syncthreads();
  float tot = red[0] + red[1] + red[2] + red[3];
  float inv = 16.0f / fmaxf(sqrtf(tot), 1e-12f);   // fp8 scale x16 folded in
  int lo = __builtin_amdgcn_cvt_pk_fp8_f32(v.x * inv, v.y * inv, 0, 0);
  int all4 = __builtin_amdgcn_cvt_pk_fp8_f32(v.z * inv, v.w * inv, lo, 1);
  reinterpret_cast<uint32_t*>(Z8 + (size_t)row * 1024)[t] = (uint32_t)all4;
}

__global__ void finalize_kernel(const float* __restrict__ S,
                                const float* __restrict__ dots,
                                float* __restrict__ out_loss)
{
  const int t = (int)threadIdx.x;  // 256
  float acc = 0.0f;
  for (int i = t; i < 2048; i += 256) {
    int tl = i & 1023;
    float w = (tl == 0 || tl == 1023) ? 1.0f : 2.0f;
    acc += w * logf(S[i] - 22026.465794806718f);
  }
  __shared__ float red[256];
  red[t] = acc;
  __syncthreads();
  for (int s2 = 128; s2 > 0; s2 >>= 1) {
    if (t < s2) red[t] += red[t + s2];
    __syncthreads();
  }
  if (t == 0) out_loss[0] = (red[0] - 20.0f * dots[0]) / 4092.0f;
}

extern "C" void kernel_launch(void* const* d_in, const int* in_sizes, int n_in,
                              void* d_out, int out_size, void* d_ws, size_t ws_size,
                              hipStream_t stream)
{
  const float* h1 = (const float*)d_in[0];
  const float* h2 = (const float*)d_in[1];
  const float* W1 = (const float*)d_in[2];
  const float* b1 = (const float*)d_in[3];
  const float* W2 = (const float*)d_in[4];
  const float* b2 = (const float*)d_in[5];
  float* out = (float*)d_out;

  char* ws = (char*)d_ws;
  u8*    X8   = (u8*)ws;                       // 16,777,216 B (fp8, x8)
  u8*    Y18  = (u8*)(ws + 16777216);          // 16,777,216 B (fp8, x8)
  u8*    W1t  = (u8*)(ws + 33554432);          //  1,048,576 B (fp8, x64)
  u8*    W2t  = (u8*)(ws + 34603008);          //  1,048,576 B (fp8, x64)
  u8*    Z8   = (u8*)(ws + 35651584);          //  2,097,152 B (fp8, x16)
  float* G    = (float*)(ws + 37748736);       // 16,777,216 B (f32 Gram)
  float* S    = (float*)(ws + 54525952);       //      8,192 B (+dots at S[2048])
  float* dots = S + 2048;

  // fused: convert_x (16384 blocks) + transpose W1/W2 (2048) + zero S/dots (1)
  prep_kernel<<<18433, 256, 0, stream>>>(h1, h2, W1, W2, X8, W1t, W2t, S);

  // layer 1: [16384,1024] @ W1 -> relu -> fp8 (256 blocks, 512 thr, MX-fp8)
  gemm_fp8<0><<<256, 512, 0, stream>>>(X8, W1t, b1, Y18, nullptr);
  // layer 2: -> relu -> fp32, transposed write into d_out ([b][t][h])
  gemm_fp8<1><<<256, 512, 0, stream>>>(Y18, W2t, b2, nullptr, out);

  // InfoNCE: fp8 Gram via the proven GEMM skeleton (simple store), then
  // a memory-bound row reduction (exp/weights/diag + superdiag dots).
  row_normalize<<<2048, 256, 0, stream>>>(out, Z8);
  gram_fp8<<<64, 512, 0, stream>>>(Z8, G);
  sim_reduce<<<2048, 256, 0, stream>>>(G, S, dots);
  finalize_kernel<<<1, 256, 0, stream>>>(S, dots, out + 16777216);
}

// Round 17
// 118.077 us; speedup vs baseline: 1.0078x; 1.0078x over previous
//
#include <hip/hip_runtime.h>
#include <cstdint>
#include <cstddef>

using u16 = unsigned short;
using u8  = unsigned char;
typedef short short8 __attribute__((ext_vector_type(8)));
typedef __bf16 bf16x8 __attribute__((ext_vector_type(8)));
typedef float f32x4 __attribute__((ext_vector_type(4)));
typedef int i32x4 __attribute__((ext_vector_type(4)));
typedef int i32x8 __attribute__((ext_vector_type(8)));

__device__ __forceinline__ u8 f2fp8(float f) {
  return (u8)(__builtin_amdgcn_cvt_pk_fp8_f32(f, f, 0, 0) & 0xFF);
}

__device__ __forceinline__ void gload16(const void* g, void* l) {
  __builtin_amdgcn_global_load_lds(
      (const __attribute__((address_space(1))) void*)g,
      (__attribute__((address_space(3))) void*)l, 16, 0, 0);
}

// =====================================================================
// MX-fp8 GEMM (R9-proven schedule), ONE template, K-loop inlined in the
// body (monolithic, R9's proven-fast module shape; no shared __device__
// core — R16's third fp8_core caller coincided with a 2x gemm slowdown).
// EPI=0: MLP-L1, fp8(relu(acc/512+b)*8) -> C8 [1024 cols]
// EPI=1: MLP-L2, f32 relu(acc/512+b) transposed -> Cf (d_out)
// EPI=2: Gram,   f32 acc/256 -> Cf [2048 cols]  (A=B=Z8, 64 blocks)
// =====================================================================
#define MFMAQ8(M0, N0, AF, BF)                                             \
  {                                                                        \
    _Pragma("unroll") for (int m_ = 0; m_ < 4; ++m_) {                     \
      _Pragma("unroll") for (int n_ = 0; n_ < 2; ++n_) {                   \
        acc[(M0) + m_][(N0) + n_] =                                        \
            __builtin_amdgcn_mfma_scale_f32_16x16x128_f8f6f4(              \
                AF[m_], BF[n_], acc[(M0) + m_][(N0) + n_],                 \
                0, 0, 0, 127, 0, 127);                                     \
      }                                                                    \
    }                                                                      \
  }

template <int EPI>
__global__ __launch_bounds__(512, 2) void gemm_fp8(
    const u8* __restrict__ A, const u8* __restrict__ Bt,
    const float* __restrict__ bias,
    u8* __restrict__ C8, float* __restrict__ Cf)
{
  constexpr int Kb = 1024, NT = 8;
  constexpr int NBN = (EPI == 2) ? 8 : 4;
  __shared__ alignas(16) u8 lds[131072];  // A: 2x32KB @0, B: 2x32KB @65536

  const int t = (int)threadIdx.x;
  const int lane = t & 63, wid = t >> 6;
  const int wr = wid >> 2, wc = wid & 3;   // 2 x 4 wave grid
  const int li = lane & 15, hk = lane >> 4;

  // bijective XCD swizzle (gridDim % 8 == 0)
  const int orig = (int)blockIdx.x;
  const int cpx = (int)gridDim.x >> 3;
  const int swz = (orig & 7) * cpx + (orig >> 3);
  const int bm = swz / NBN, bn = swz % NBN;
  const int arow0 = bm * 256, brow0 = bn * 256;

  const int Rl = lane >> 3;
  const int sc16 = ((lane & 7) ^ Rl) << 4;
  const int wid2 = wid * 2;

  const int c0b = (((hk << 1) + 0) ^ (li & 7)) << 4;
  const int c1b = (((hk << 1) + 1) ^ (li & 7)) << 4;

  f32x4 acc[8][4];
#pragma unroll
  for (int m = 0; m < 8; ++m)
#pragma unroll
    for (int n = 0; n < 4; ++n)
#pragma unroll
      for (int j = 0; j < 4; ++j) acc[m][n][j] = 0.0f;

  auto STAGE = [&](const u8* G, int growbase, int tau, int ldsoff) {
#pragma unroll
    for (int l = 0; l < 2; ++l) {
      const u8* g = G + (size_t)(growbase + (wid2 + l) * 8 + Rl) * Kb +
                    tau * 128 + sc16;
      gload16(g, lds + ldsoff + (wid2 + l) * 1024);
    }
  };
  auto RD = [&](const u8* base, int row) -> i32x8 {
    const u8* p = base + row * 128;
    i32x4 lo = *reinterpret_cast<const i32x4*>(p + c0b);
    i32x4 hi = *reinterpret_cast<const i32x4*>(p + c1b);
    i32x8 r;
    r[0] = lo[0]; r[1] = lo[1]; r[2] = lo[2]; r[3] = lo[3];
    r[4] = hi[0]; r[5] = hi[1]; r[6] = hi[2]; r[7] = hi[3];
    return r;
  };

  i32x8 aa[4], bb01[2], bb23[2];

  STAGE(Bt, brow0 + 0,   0, 65536 + 0);
  STAGE(Bt, brow0 + 128, 0, 65536 + 16384);
  STAGE(A,  arow0 + 0,   0, 0);
  STAGE(A,  arow0 + 128, 0, 16384);
  STAGE(Bt, brow0 + 0,   1, 65536 + 32768);
  STAGE(Bt, brow0 + 128, 1, 65536 + 32768 + 16384);
  STAGE(A,  arow0 + 0,   1, 32768);
  STAGE(A,  arow0 + 128, 1, 32768 + 16384);
  asm volatile("s_waitcnt vmcnt(8)" ::: "memory");
  __builtin_amdgcn_s_barrier();

  {
    const u8* Ab0 = lds + wr * 16384;
    const u8* Bb0 = lds + 65536 + wc * 8192;
#pragma unroll
    for (int m = 0; m < 4; ++m) aa[m] = RD(Ab0, m * 16 + li);
#pragma unroll
    for (int n = 0; n < 2; ++n) bb01[n] = RD(Bb0, n * 16 + li);
  }

  for (int tau = 0; tau < NT; ++tau) {
    const int cur = tau & 1, nxt = cur ^ 1;
    const u8* Ab  = lds + cur * 32768 + wr * 16384;
    const u8* Bb  = lds + 65536 + cur * 32768 + wc * 8192;
    const u8* Abn = lds + nxt * 32768 + wr * 16384;
    const u8* Bbn = lds + 65536 + nxt * 32768 + wc * 8192;

#pragma unroll
    for (int n = 0; n < 2; ++n) bb23[n] = RD(Bb, 32 + n * 16 + li);
    asm volatile("s_waitcnt lgkmcnt(4)" ::: "memory");
    __builtin_amdgcn_sched_barrier(0);
    __builtin_amdgcn_s_setprio(1);
    MFMAQ8(0, 0, aa, bb01);
    __builtin_amdgcn_s_setprio(0);

    asm volatile("s_waitcnt lgkmcnt(0)" ::: "memory");
    __builtin_amdgcn_sched_barrier(0);
    __builtin_amdgcn_s_setprio(1);
    MFMAQ8(0, 2, aa, bb23);
    __builtin_amdgcn_s_setprio(0);
    __builtin_amdgcn_sched_barrier(0);
#pragma unroll
    for (int m = 0; m < 4; ++m) aa[m] = RD(Ab, (m + 4) * 16 + li);
    __builtin_amdgcn_s_barrier();

    if (tau + 2 < NT) {
      STAGE(Bt, brow0 + 0,   tau + 2, 65536 + cur * 32768);
      STAGE(Bt, brow0 + 128, tau + 2, 65536 + cur * 32768 + 16384);
    }
    asm volatile("s_waitcnt lgkmcnt(0)" ::: "memory");
    __builtin_amdgcn_sched_barrier(0);
    __builtin_amdgcn_s_setprio(1);
    MFMAQ8(4, 2, aa, bb23);
    __builtin_amdgcn_s_setprio(0);
    __builtin_amdgcn_s_barrier();

    if (tau + 2 < NT) {
      STAGE(A, arow0 + 0,   tau + 2, cur * 32768);
      STAGE(A, arow0 + 128, tau + 2, cur * 32768 + 16384);
      asm volatile("s_waitcnt vmcnt(8)" ::: "memory");
    } else if (tau + 1 < NT) {
      asm volatile("s_waitcnt vmcnt(0)" ::: "memory");
    }
    __builtin_amdgcn_s_barrier();
    __builtin_amdgcn_s_setprio(1);
    MFMAQ8(4, 0, aa, bb01);
    __builtin_amdgcn_s_setprio(0);
    __builtin_amdgcn_sched_barrier(0);
    if (tau + 1 < NT) {
#pragma unroll
      for (int m = 0; m < 4; ++m) aa[m] = RD(Abn, m * 16 + li);
#pragma unroll
      for (int n = 0; n < 2; ++n) bb01[n] = RD(Bbn, n * 16 + li);
    }
  }

  // ---- epilogue (simple stores only; fused exp/atomics spill — R13) ----
#pragma unroll
  for (int m = 0; m < 8; ++m) {
#pragma unroll
    for (int n = 0; n < 4; ++n) {
      const int gcol = brow0 + wc * 64 + n * 16 + li;
      float bv = 0.0f;
      if (EPI < 2) bv = bias[gcol];
#pragma unroll
      for (int j = 0; j < 4; ++j) {
        const int grow = arow0 + wr * 128 + m * 16 + hk * 4 + j;
        if (EPI == 0) {
          float v = fmaxf(acc[m][n][j] * 0.001953125f + bv, 0.0f);
          C8[(size_t)grow * 1024 + gcol] = f2fp8(v * 8.0f);
        } else if (EPI == 1) {
          float v = fmaxf(acc[m][n][j] * 0.001953125f + bv, 0.0f);
          int tensor = grow >> 13, rr = grow & 8191;
          int tt = rr >> 3, b_ = rr & 7;
          Cf[(size_t)tensor * 8388608 + (size_t)b_ * 1048576 +
             (size_t)tt * 1024 + gcol] = v;
        } else {
          Cf[(size_t)grow * 2048 + gcol] = acc[m][n][j] * 0.00390625f;
        }
      }
    }
  }
}

// ---------------- sim_reduce: S[row] = sum_col w*exp(10*G'); dots fold ----
__global__ __launch_bounds__(256) void sim_reduce(
    const float* __restrict__ G, float* __restrict__ S,
    float* __restrict__ dots)
{
  const int row = (int)blockIdx.x;
  const int t = (int)threadIdx.x;
  const float* gp = G + (size_t)row * 2048 + t * 8;
  float4 v0 = *reinterpret_cast<const float4*>(gp);
  float4 v1 = *reinterpret_cast<const float4*>(gp + 4);
  float vals[8] = {v0.x, v0.y, v0.z, v0.w, v1.x, v1.y, v1.z, v1.w};
  float s = 0.0f, d = 0.0f;
#pragma unroll
  for (int e = 0; e < 8; ++e) {
    int col = t * 8 + e;
    float g = vals[e];
    float logit = (col == row) ? 10.0f : g * 10.0f;
    float w = (col == 0 || col == 1023 || col == 1024 || col == 2047)
                  ? 1.0f : 2.0f;
    s += w * expf(logit);
    if (col == row + 1 && (row & 1023) != 1023) d += g;
  }
#pragma unroll
  for (int o = 1; o < 64; o <<= 1) {
    s += __shfl_xor(s, o);
    d += __shfl_xor(d, o);
  }
  __shared__ float rs[4], rd[4];
  if ((t & 63) == 0) { rs[t >> 6] = s; rd[t >> 6] = d; }
  __syncthreads();
  if (t == 0) {
    S[row] = rs[0] + rs[1] + rs[2] + rs[3];
    atomicAdd(dots, rd[0] + rd[1] + rd[2] + rd[3]);
  }
}

// ---------------- fused prep: convert_x(fp8,x8) + transpose W(fp8,x64) + zero S/dots
__global__ void prep_kernel(const float* __restrict__ h1,
                            const float* __restrict__ h2,
                            const float* __restrict__ W1,
                            const float* __restrict__ W2,
                            u8* __restrict__ X8,
                            u8* __restrict__ W1t,
                            u8* __restrict__ W2t,
                            float* __restrict__ S)
{
  __shared__ float tile[32][33];
  int bid = (int)blockIdx.x;
  if (bid < 16384) {
    size_t i4 = ((size_t)bid * 256 + threadIdx.x) * 4;
    const float* src = (i4 < 8388608) ? (h1 + i4) : (h2 + (i4 - 8388608));
    float4 v = *reinterpret_cast<const float4*>(src);
    int lo = __builtin_amdgcn_cvt_pk_fp8_f32(v.x * 8.0f, v.y * 8.0f, 0, 0);
    int all4 = __builtin_amdgcn_cvt_pk_fp8_f32(v.z * 8.0f, v.w * 8.0f, lo, 1);
    *reinterpret_cast<uint32_t*>(X8 + i4) = (uint32_t)all4;
    return;
  }
  bid -= 16384;
  const float* W;
  u8* Wt;
  if (bid < 1024) {
    W = W1; Wt = W1t;
  } else if (bid < 2048) {
    W = W2; Wt = W2t; bid -= 1024;
  } else {
    for (int i = (int)threadIdx.x; i < 2064; i += 256) S[i] = 0.0f;
    return;
  }
  const int bx = bid & 31, by = bid >> 5;
  const int tx = (int)threadIdx.x & 31, ty = (int)threadIdx.x >> 5;
#pragma unroll
  for (int i = 0; i < 4; ++i)
    tile[ty + i * 8][tx] = W[(size_t)(by * 32 + ty + i * 8) * 1024 + bx * 32 + tx];
  __syncthreads();
#pragma unroll
  for (int i = 0; i < 4; ++i)
    Wt[(size_t)(bx * 32 + ty + i * 8) * 1024 + by * 32 + tx] =
        f2fp8(tile[tx][ty + i * 8] * 64.0f);
}

// ---------------- row_normalize: out rows -> fp8 z*16 (R13-proven) ----------------
__global__ void row_normalize(const float* __restrict__ out, u8* __restrict__ Z8)
{
  const int row = (int)blockIdx.x;   // 0..2047
  const int t = (int)threadIdx.x;    // 256
  const float* src = out + ((row < 1024)
      ? ((size_t)7 * 1048576 + (size_t)row * 1024)
      : ((size_t)8388608 + (size_t)7 * 1048576 + (size_t)(row - 1024) * 1024));
  float4 v = reinterpret_cast<const float4*>(src)[t];
  float ss = v.x * v.x + v.y * v.y + v.z * v.z + v.w * v.w;
#pragma unroll
  for (int d = 1; d < 64; d <<= 1) ss += __shfl_xor(ss, d);
  __shared__ float red[4];
  if ((t & 63) == 0) red[t >> 6] = ss;
  __syncthreads();
  float tot = red[0] + red[1] + red[2] + red[3];
  float inv = 16.0f / fmaxf(sqrtf(tot), 1e-12f);
  int lo = __builtin_amdgcn_cvt_pk_fp8_f32(v.x * inv, v.y * inv, 0, 0);
  int all4 = __builtin_amdgcn_cvt_pk_fp8_f32(v.z * inv, v.w * inv, lo, 1);
  reinterpret_cast<uint32_t*>(Z8 + (size_t)row * 1024)[t] = (uint32_t)all4;
}

__global__ void finalize_kernel(const float* __restrict__ S,
                                const float* __restrict__ dots,
                                float* __restrict__ out_loss)
{
  const int t = (int)threadIdx.x;  // 256
  float acc = 0.0f;
  for (int i = t; i < 2048; i += 256) {
    int tl = i & 1023;
    float w = (tl == 0 || tl == 1023) ? 1.0f : 2.0f;
    acc += w * logf(S[i] - 22026.465794806718f);
  }
  __shared__ float red[256];
  red[t] = acc;
  __syncthreads();
  for (int s2 = 128; s2 > 0; s2 >>= 1) {
    if (t < s2) red[t] += red[t + s2];
    __syncthreads();
  }
  if (t == 0) out_loss[0] = (red[0] - 20.0f * dots[0]) / 4092.0f;
}

extern "C" void kernel_launch(void* const* d_in, const int* in_sizes, int n_in,
                              void* d_out, int out_size, void* d_ws, size_t ws_size,
                              hipStream_t stream)
{
  const float* h1 = (const float*)d_in[0];
  const float* h2 = (const float*)d_in[1];
  const float* W1 = (const float*)d_in[2];
  const float* b1 = (const float*)d_in[3];
  const float* W2 = (const float*)d_in[4];
  const float* b2 = (const float*)d_in[5];
  float* out = (float*)d_out;

  char* ws = (char*)d_ws;
  u8*    X8   = (u8*)ws;                       // 16,777,216 B (fp8, x8)
  u8*    Y18  = (u8*)(ws + 16777216);          // 16,777,216 B (fp8, x8)
  u8*    W1t  = (u8*)(ws + 33554432);          //  1,048,576 B (fp8, x64)
  u8*    W2t  = (u8*)(ws + 34603008);          //  1,048,576 B (fp8, x64)
  u8*    Z8   = (u8*)(ws + 35651584);          //  2,097,152 B (fp8, x16)
  float* G    = (float*)(ws + 37748736);       // 16,777,216 B (f32 Gram)
  float* S    = (float*)(ws + 54525952);       //      8,192 B (+dots at S[2048])
  float* dots = S + 2048;

  // fused: convert_x (16384 blocks) + transpose W1/W2 (2048) + zero S/dots (1)
  prep_kernel<<<18433, 256, 0, stream>>>(h1, h2, W1, W2, X8, W1t, W2t, S);

  // layer 1: [16384,1024] @ W1 -> relu -> fp8
  gemm_fp8<0><<<256, 512, 0, stream>>>(X8, W1t, b1, Y18, nullptr);
  // layer 2: -> relu -> fp32, transposed write into d_out ([b][t][h])
  gemm_fp8<1><<<256, 512, 0, stream>>>(Y18, W2t, b2, nullptr, out);

  // InfoNCE: Gram via the same GEMM template (simple store), then reduce.
  row_normalize<<<2048, 256, 0, stream>>>(out, Z8);
  gemm_fp8<2><<<64, 512, 0, stream>>>(Z8, Z8, nullptr, nullptr, G);
  sim_reduce<<<2048, 256, 0, stream>>>(G, S, dots);
  finalize_kernel<<<1, 256, 0, stream>>>(S, dots, out + 16777216);
}